// Round 1
// baseline (226.079 us; speedup 1.0000x reference)
//
#include <hip/hip_runtime.h>
#include <hip/hip_bf16.h>

// ChannelKiller: out[b,c,t] = x[b,c,t] * (c==0 ? 1.0f : 0.5f)
// Shapes: B=16, C=8, T=262144 (fp32). Flat float4 index i4 -> channel = (i4>>16)&7
// because T/4 = 65536 = 2^16 and C = 8.
//
// Memory-bound: 268 MB total traffic, floor ~42.6 us @ 6.3 TB/s achievable.

__global__ void __launch_bounds__(256)
channel_killer_kernel(const float4* __restrict__ x, float4* __restrict__ out, int n4) {
    int i = blockIdx.x * blockDim.x + threadIdx.x;
    const int stride = gridDim.x * blockDim.x;
    for (; i < n4; i += stride) {
        float4 v = x[i];
        // channel of this float4: (i >> 16) & 7 ; scale 1.0 for c==0 else 0.5
        const float s = ((i >> 16) & 7) == 0 ? 1.0f : 0.5f;
        v.x *= s; v.y *= s; v.z *= s; v.w *= s;
        out[i] = v;
    }
}

extern "C" void kernel_launch(void* const* d_in, const int* in_sizes, int n_in,
                              void* d_out, int out_size, void* d_ws, size_t ws_size,
                              hipStream_t stream) {
    const float4* x = (const float4*)d_in[0];
    float4* out = (float4*)d_out;
    const int n = in_sizes[0];          // 33,554,432
    const int n4 = n >> 2;              // 8,388,608 float4s

    const int block = 256;
    const int grid = 8192;              // grid-stride: 4 float4s per thread
    channel_killer_kernel<<<grid, block, 0, stream>>>(x, out, n4);
}